// Round 9
// baseline (385.191 us; speedup 1.0000x reference)
//
#include <hip/hip_runtime.h>
#include <cstdint>
#include <cstddef>

#define L_SEQ 4096
#define BATCH 32
#define DIN 128
#define DLAT 512
#define CHUNK 32
#define NCHUNK (L_SEQ / CHUNK)   // 128
#define MC 4                     // chunks per block in kernel A
#define NCH 4                    // channels per thread in kernel A

__device__ __forceinline__ void async_copy16(const float* g, float* l) {
    __builtin_amdgcn_global_load_lds(
        (const __attribute__((address_space(1))) unsigned int*)g,
        (__attribute__((address_space(3))) unsigned int*)l,
        16, 0, 0);
}

// Quad-perm DPP cross-lane adds (lanes tid&3 form a DPP quad). Pure VALU.
__device__ __forceinline__ float dpp_add_xor1(float x) {
    int r = __builtin_amdgcn_update_dpp(0, __builtin_bit_cast(int, x),
                                        0xB1, 0xF, 0xF, true);
    return x + __builtin_bit_cast(float, r);
}
__device__ __forceinline__ float dpp_add_xor2(float x) {
    int r = __builtin_amdgcn_update_dpp(0, __builtin_bit_cast(int, x),
                                        0x4E, 0xF, 0xF, true);
    return x + __builtin_bit_cast(float, r);
}

// ---------------------------------------------------------------------------
// Kernel A: fused GEMM + chunk-local scan. 4 channels/thread, 4 chunks/block,
// double-buffered LDS staging. grid (NCHUNK/MC, BATCH, 2), block 256.
// launch_bounds(256,1): 512-reg unified budget so wxr[4][32]=128 floats stays
// in ARCH VGPRs (round-8's (256,2) forced a 96-arch/160-AGPR split -> one
// accvgpr move per FMA operand -> VALUBusy pinned at 61%).
// ---------------------------------------------------------------------------
__global__ __launch_bounds__(256, 1) void rnn_local(
    const float* __restrict__ X,   // [L, B, DIN]
    const float* __restrict__ wx,  // [DIN, DLAT]
    const float* __restrict__ wh,  // [DLAT]
    const float* __restrict__ bh,  // [DLAT]
    float* __restrict__ out,       // [L, B, DLAT]  (scratch: pre-tanh locals)
    float* __restrict__ F)         // [NCHUNK, B, DLAT] chunk-final locals
{
    __shared__ float Xs[2][CHUNK * DIN];  // 2 x 16 KiB, double buffer

    const int tid = threadIdx.x;
    const int c0 = blockIdx.x * MC;    // first chunk of this block
    const int b  = blockIdx.y;
    const int jg = blockIdx.z;         // 0..1, 256 channels per group
    const int ch = tid >> 2;           // 0..63
    const int r  = tid & 3;            // K-slice 0..3

    // Staging: shot s stages timesteps 8s..8s+7 of chunk c.
    // ts = tid>>5 (0..7), k = (tid&31)*4. LDS float idx = s*1024 + tid*4
    // == (8s+ts)*128 + k  -> Xs[buf][t*128+k], linear in tid per shot.
    const int ts  = tid >> 5;
    const int k16 = (tid & 31) * 4;
    const float* gbase = X + ((size_t)ts * BATCH + b) * DIN + k16;

#define STAGE(cc, buf)                                                          \
    {                                                                           \
        const float* g0 = gbase + (size_t)(cc) * CHUNK * BATCH * DIN;           \
        float* l0 = &Xs[buf][0] + tid * 4;                                      \
        _Pragma("unroll")                                                       \
        for (int s = 0; s < 4; ++s)                                             \
            async_copy16(g0 + (size_t)s * 8 * BATCH * DIN, l0 + s * 1024);      \
    }

    // Prologue: stage first chunk into buffer 0, load weights meanwhile.
    STAGE(c0, 0)

    // wx slices for 4 channels: k = 8*r + 32*s + i
    float wxr[NCH][32];
    int jn[NCH];
    float whn[NCH], bh4[NCH];
#pragma unroll
    for (int n = 0; n < NCH; ++n) {
        jn[n] = jg * 256 + n * 64 + ch;
        whn[n] = wh[jn[n]];
        bh4[n] = bh[jn[n]] * 0.25f;   // exact scale; 4 lanes sum to +bh
    }
#pragma unroll
    for (int s = 0; s < 4; ++s)
#pragma unroll
        for (int i = 0; i < 8; ++i) {
            const size_t krow = (size_t)(8 * r + 32 * s + i) * DLAT;
#pragma unroll
            for (int n = 0; n < NCH; ++n)
                wxr[n][s * 8 + i] = wx[krow + jn[n]];
        }

    asm volatile("s_waitcnt vmcnt(0)" ::: "memory");
    __syncthreads();

    for (int m = 0; m < MC; ++m) {
        const int c   = c0 + m;
        const int buf = m & 1;
        if (m + 1 < MC)
            STAGE(c + 1, (m + 1) & 1)   // async into other buffer during compute

        float l[NCH] = {0.f, 0.f, 0.f, 0.f};

        for (int g = 0; g < 8; ++g) {
            float snap[NCH] = {0.f, 0.f, 0.f, 0.f};
#pragma unroll
            for (int q = 0; q < 4; ++q) {
                const float* xt = &Xs[buf][0] + (g * 4 + q) * DIN + 8 * r;
                float acc[NCH] = {bh4[0], bh4[1], bh4[2], bh4[3]};
#pragma unroll
                for (int s = 0; s < 4; ++s) {
                    const float4 xa = *(const float4*)(xt + 32 * s);
                    const float4 xc = *(const float4*)(xt + 32 * s + 4);
#pragma unroll
                    for (int n = 0; n < NCH; ++n) {
                        acc[n] = fmaf(xa.x, wxr[n][s * 8 + 0], acc[n]);
                        acc[n] = fmaf(xa.y, wxr[n][s * 8 + 1], acc[n]);
                        acc[n] = fmaf(xa.z, wxr[n][s * 8 + 2], acc[n]);
                        acc[n] = fmaf(xa.w, wxr[n][s * 8 + 3], acc[n]);
                        acc[n] = fmaf(xc.x, wxr[n][s * 8 + 4], acc[n]);
                        acc[n] = fmaf(xc.y, wxr[n][s * 8 + 5], acc[n]);
                        acc[n] = fmaf(xc.z, wxr[n][s * 8 + 6], acc[n]);
                        acc[n] = fmaf(xc.w, wxr[n][s * 8 + 7], acc[n]);
                    }
                }
#pragma unroll
                for (int n = 0; n < NCH; ++n) {
                    float a = dpp_add_xor1(acc[n]);
                    a = dpp_add_xor2(a);
                    l[n] = fmaf(l[n], whn[n], a);   // a already includes bh
                    snap[n] = (q == r) ? l[n] : snap[n];
                }
            }
            const int t = c * CHUNK + g * 4 + r;
            const size_t row = (size_t)t * (BATCH * DLAT) + (size_t)b * DLAT;
#pragma unroll
            for (int n = 0; n < NCH; ++n)
                out[row + jn[n]] = snap[n];
        }

        if (r == 0) {
            const size_t fb = ((size_t)c * BATCH + b) * DLAT;
#pragma unroll
            for (int n = 0; n < NCH; ++n)
                F[fb + jn[n]] = l[n];
        }

        asm volatile("s_waitcnt vmcnt(0)" ::: "memory");
        __syncthreads();
    }
#undef STAGE
}

// ---------------------------------------------------------------------------
// Kernel B0: sequential prefix over chunks -> Hpre[c] = state entering chunk c.
// grid (BATCH), block 128 (thread owns float4 of channels). Tiny.
// ---------------------------------------------------------------------------
__global__ __launch_bounds__(128) void rnn_prefix(
    const float* __restrict__ h0,   // [B, DLAT]
    const float* __restrict__ wh,   // [DLAT]
    const float* __restrict__ F,    // [NCHUNK, B, DLAT]
    float* __restrict__ Hpre)       // [NCHUNK, B, DLAT]
{
    const int b  = blockIdx.x;
    const int j4 = threadIdx.x * 4;
    const size_t cb = (size_t)b * DLAT + j4;

    float4 w4 = *(const float4*)(wh + j4);
    float wv[4] = {w4.x, w4.y, w4.z, w4.w};
    float wc[4];
#pragma unroll
    for (int k = 0; k < 4; ++k) {
        float t = wv[k];
        t = t * t; t = t * t; t = t * t; t = t * t; t = t * t;  // wh^32 (>0)
        wc[k] = t;
    }

    float4 h4 = *(const float4*)(h0 + cb);
    float Hv[4] = {h4.x, h4.y, h4.z, h4.w};

    for (int cg = 0; cg < NCHUNK / 4; ++cg) {
        float4 Fv[4];
#pragma unroll
        for (int i = 0; i < 4; ++i)
            Fv[i] = *(const float4*)(F + (size_t)(cg * 4 + i) * (BATCH * DLAT) + cb);
#pragma unroll
        for (int i = 0; i < 4; ++i) {
            float4 o = {Hv[0], Hv[1], Hv[2], Hv[3]};
            *(float4*)(Hpre + (size_t)(cg * 4 + i) * (BATCH * DLAT) + cb) = o;
            Hv[0] = fmaf(Hv[0], wc[0], Fv[i].x);
            Hv[1] = fmaf(Hv[1], wc[1], Fv[i].y);
            Hv[2] = fmaf(Hv[2], wc[2], Fv[i].z);
            Hv[3] = fmaf(Hv[3], wc[3], Fv[i].w);
        }
    }
}

// ---------------------------------------------------------------------------
// Kernel C: pure streaming fixup: out_t = tanh(l_t + wh^{d+1} * Hpre[c]).
// grid (NCHUNK/2, BATCH), block 256 = 2 chunks x 128 threads x float4.
// ---------------------------------------------------------------------------
__global__ __launch_bounds__(256) void rnn_fix2(
    const float* __restrict__ wh,    // [DLAT]
    const float* __restrict__ Hpre,  // [NCHUNK, B, DLAT]
    float* __restrict__ out)         // [L, B, DLAT] in-place
{
    const int tid = threadIdx.x;
    const int c   = blockIdx.x * 2 + (tid >> 7);
    const int b   = blockIdx.y;
    const int j4  = (tid & 127) * 4;
    const size_t cb = (size_t)b * DLAT + j4;

    float4 w4 = *(const float4*)(wh + j4);
    float4 H4 = *(const float4*)(Hpre + (size_t)c * (BATCH * DLAT) + cb);
    float wv[4] = {w4.x, w4.y, w4.z, w4.w};
    float Hv[4] = {H4.x, H4.y, H4.z, H4.w};

    float sc[4] = {wv[0], wv[1], wv[2], wv[3]};
#pragma unroll 4
    for (int d = 0; d < CHUNK; ++d) {
        const size_t off = ((size_t)(c * CHUNK + d) * BATCH + b) * DLAT + j4;
        float4 l4 = *(const float4*)(out + off);
        float4 res;
        res.x = tanhf(fmaf(sc[0], Hv[0], l4.x));
        res.y = tanhf(fmaf(sc[1], Hv[1], l4.y));
        res.z = tanhf(fmaf(sc[2], Hv[2], l4.z));
        res.w = tanhf(fmaf(sc[3], Hv[3], l4.w));
        *(float4*)(out + off) = res;
        sc[0] *= wv[0]; sc[1] *= wv[1]; sc[2] *= wv[2]; sc[3] *= wv[3];
    }
}

// Fallback (ws too small for Hpre): fold H per block from F, as in round 6.
__global__ __launch_bounds__(256) void rnn_fix(
    const float* __restrict__ h0, const float* __restrict__ wh,
    const float* __restrict__ F, float* __restrict__ out)
{
    const int tid = threadIdx.x;
    const int c   = blockIdx.x * 2 + (tid >> 7);
    const int b   = blockIdx.y;
    const int j4  = (tid & 127) * 4;
    const size_t cb = (size_t)b * DLAT + j4;

    float4 h4 = *(const float4*)(h0 + cb);
    float4 w4 = *(const float4*)(wh + j4);
    float Hv[4] = {h4.x, h4.y, h4.z, h4.w};
    float wv[4] = {w4.x, w4.y, w4.z, w4.w};
    float wc[4];
#pragma unroll
    for (int k = 0; k < 4; ++k) {
        float t = wv[k];
        t = t * t; t = t * t; t = t * t; t = t * t; t = t * t;
        wc[k] = t;
    }
    for (int cc = 0; cc < c; ++cc) {
        const float4 Fv = *(const float4*)(F + ((size_t)cc * BATCH + b) * DLAT + j4);
        Hv[0] = fmaf(Hv[0], wc[0], Fv.x);
        Hv[1] = fmaf(Hv[1], wc[1], Fv.y);
        Hv[2] = fmaf(Hv[2], wc[2], Fv.z);
        Hv[3] = fmaf(Hv[3], wc[3], Fv.w);
    }
    float sc[4] = {wv[0], wv[1], wv[2], wv[3]};
    for (int d = 0; d < CHUNK; ++d) {
        const size_t off = ((size_t)(c * CHUNK + d) * BATCH + b) * DLAT + j4;
        float4 l4 = *(const float4*)(out + off);
        float4 res;
        res.x = tanhf(fmaf(sc[0], Hv[0], l4.x));
        res.y = tanhf(fmaf(sc[1], Hv[1], l4.y));
        res.z = tanhf(fmaf(sc[2], Hv[2], l4.z));
        res.w = tanhf(fmaf(sc[3], Hv[3], l4.w));
        *(float4*)(out + off) = res;
        sc[0] *= wv[0]; sc[1] *= wv[1]; sc[2] *= wv[2]; sc[3] *= wv[3];
    }
}

extern "C" void kernel_launch(void* const* d_in, const int* in_sizes, int n_in,
                              void* d_out, int out_size, void* d_ws, size_t ws_size,
                              hipStream_t stream) {
    const float* X  = (const float*)d_in[0];
    const float* h0 = (const float*)d_in[1];
    const float* wx = (const float*)d_in[2];
    const float* wh = (const float*)d_in[3];
    const float* bh = (const float*)d_in[4];
    float* out = (float*)d_out;

    const size_t seg = (size_t)NCHUNK * BATCH * DLAT;  // 2M floats = 8 MiB
    float* F    = (float*)d_ws;
    float* Hpre = F + seg;

    rnn_local<<<dim3(NCHUNK / MC, BATCH, 2), dim3(256), 0, stream>>>(X, wx, wh, bh, out, F);
    if (ws_size >= 2 * seg * sizeof(float)) {
        rnn_prefix<<<dim3(BATCH), dim3(128), 0, stream>>>(h0, wh, F, Hpre);
        rnn_fix2<<<dim3(NCHUNK / 2, BATCH), dim3(256), 0, stream>>>(wh, Hpre, out);
    } else {
        rnn_fix<<<dim3(NCHUNK / 2, BATCH), dim3(256), 0, stream>>>(h0, wh, F, out);
    }
}